// Round 6
// baseline (631.332 us; speedup 1.0000x reference)
//
#include <hip/hip_runtime.h>
#include <math.h>

namespace {

typedef _Float16 f16;
typedef _Float16 f16x8 __attribute__((ext_vector_type(8)));
typedef float    f32x4 __attribute__((ext_vector_type(4)));

constexpr int kBT = 1024, kD1 = 256, kD2 = 128, kDM = 1024, kV = 32000, kK = 4;
constexpr int AR = kBT * kK;                    // 4096 rows of (bt,k)
constexpr int ROWS_H = kK * kDM;                // 4096
constexpr int ROWS_U = kK * kD2;                // 512
constexpr int ROWS_ALL = ROWS_H + ROWS_U + kK;  // 4612
constexpr int HALF_ROWS = ROWS_ALL / 2;         // 2306

// ---------------------------------------------------------------------------
// prep_gemm: hc/tU/ug from gc (fp32 accumulate, fp16 store).
// ---------------------------------------------------------------------------
__global__ __launch_bounds__(256) void prep_gemm(
    const float* __restrict__ gc, const float* __restrict__ Hm,
    const float* __restrict__ Um, const float* __restrict__ um,
    f16* __restrict__ hc, f16* __restrict__ tu, float* __restrict__ ug)
{
    __shared__ float sgc[8][kD1];
    const int btBase = blockIdx.x * 8;
    for (int idx = threadIdx.x; idx < 8 * kD1; idx += 256)
        sgc[idx / kD1][idx % kD1] = gc[(size_t)btBase * kD1 + idx];
    __syncthreads();

    const int rStart = blockIdx.y * HALF_ROWS;
    const int rEnd   = rStart + HALF_ROWS;
    for (int r = rStart + (int)threadIdx.x; r < rEnd; r += 256) {
        const float* wrow;
        if (r < ROWS_H)               wrow = Hm + (size_t)r * kD1;
        else if (r < ROWS_H + ROWS_U) wrow = Um + (size_t)(r - ROWS_H) * kD1;
        else                          wrow = um + (size_t)(r - ROWS_H - ROWS_U) * kD1;

        float acc[8] = {0.f,0.f,0.f,0.f,0.f,0.f,0.f,0.f};
        for (int i = 0; i < kD1; i += 4) {
            const float4 w = *reinterpret_cast<const float4*>(wrow + i);
            #pragma unroll
            for (int b = 0; b < 8; ++b) {
                const float4 g = *reinterpret_cast<const float4*>(&sgc[b][i]);
                acc[b] = fmaf(w.x, g.x, acc[b]);
                acc[b] = fmaf(w.y, g.y, acc[b]);
                acc[b] = fmaf(w.z, g.z, acc[b]);
                acc[b] = fmaf(w.w, g.w, acc[b]);
            }
        }
        #pragma unroll
        for (int b = 0; b < 8; ++b) {
            const int bt = btBase + b;
            if (r < ROWS_H) {
                const int k = r >> 10, d = r & 1023;
                hc[((size_t)(bt * kK + k) << 10) + d] = (f16)tanhf(acc[b]);
            } else if (r < ROWS_H + ROWS_U) {
                const int r2 = r - ROWS_H;
                const int k = r2 >> 7, j = r2 & 127;
                tu[(size_t)(bt * kK + k) * kD2 + j] = (f16)tanhf(acc[b]);
            } else {
                ug[bt * kK + (r - ROWS_H - ROWS_U)] = acc[b];
            }
        }
    }
}

// ---------------------------------------------------------------------------
// cvt_kernel: fp32 -> fp16, 8 elems/thread.
// ---------------------------------------------------------------------------
__global__ __launch_bounds__(256) void cvt_kernel(
    const float* __restrict__ src, f16* __restrict__ dst, int n8)
{
    const int i = blockIdx.x * 256 + threadIdx.x;
    if (i >= n8) return;
    const float4 x0 = *reinterpret_cast<const float4*>(src + (size_t)i * 8);
    const float4 x1 = *reinterpret_cast<const float4*>(src + (size_t)i * 8 + 4);
    union { f16 h[8]; uint4 v; } u;
    u.h[0] = (f16)x0.x; u.h[1] = (f16)x0.y; u.h[2] = (f16)x0.z; u.h[3] = (f16)x0.w;
    u.h[4] = (f16)x1.x; u.h[5] = (f16)x1.y; u.h[6] = (f16)x1.z; u.h[7] = (f16)x1.w;
    *reinterpret_cast<uint4*>(dst + (size_t)i * 8) = u.v;
}

__device__ __forceinline__ uint packf16x2(float a, float b) {
    union { f16 h[2]; uint u; } z;
    z.h[0] = (f16)a; z.h[1] = (f16)b;
    return z.u;
}

// ---------------------------------------------------------------------------
// fused_mfma: gate GEMM (K=128) + dots GEMM (K=1024), one 36-half stream.
// BM=256 A-rows x BN=128 v, BK=64 in 32-col halves; 8 waves (4M x 2N),
// wave-tile 64x64. LDS: ring of 4 half-slots, A 16KB + B 8KB each = 96 KiB,
// LINEAR layout (32-col rows = 64B: b128 reads are 8 lanes/4-bank-group =
// conflict-free; gload_lds writes linear 1KB/wave).
// Pipeline: 3 halves prefetched ahead (3 loads/half/thread). Per phase:
//   {8x ds_read_b128; issue 3 gload_lds of half g+3; s_waitcnt vmcnt(6);
//    s_barrier; setprio(1); 16 MFMA; setprio(0); s_barrier}
// vmcnt(6) retires half g+1 (allowed in flight: halves g+2,g+3 = 6 loads).
// WAR safety: half g+4 (same slot as g) is issued in phase g+1, after
// bar2_g; all waves' ds_reads of half g were lgkm-completed before their
// MFMA_g, which precedes bar2_g. Tail vmcnts 6 -> 3 -> 0.
// A rows = (bt*4+k): acc reg j = mixture component k of one (bt,v).
// ---------------------------------------------------------------------------
__global__ __launch_bounds__(512, 2) void fused_mfma(
    const f16* __restrict__ hc,  const f16* __restrict__ tu,
    const f16* __restrict__ v16, const f16* __restrict__ e16,
    const float* __restrict__ ug, const float* __restrict__ bmat,
    float* __restrict__ out)
{
    __shared__ __align__(16) f16 sA[4][256 * 32];   // 64 KiB
    __shared__ __align__(16) f16 sB[4][128 * 32];   // 32 KiB

    const int tid  = threadIdx.x;
    const int lane = tid & 63;
    const int wave = tid >> 6;
    const int fr = lane & 15, fq = lane >> 4;
    const int wm = wave >> 1, wc = wave & 1;

    // XCD-aware bijective map: 4000 blocks = 8 XCDs x 500; per XCD 2 bx-panels
    // x 250 by (consecutive idx share bx -> A-panel L2-resident per XCD).
    const int wg  = blockIdx.x;
    const int idx = wg >> 3;
    const int bx  = (wg & 7) * 2 + idx / 250;   // 0..15
    const int by  = idx % 250;                  // 0..249
    const int aRowBase = bx * 256;
    const int vBase    = by * 128;

    // staging lane geometry (linear): lane l -> row l>>2, 16B slot l&3.
    const int srowL = lane >> 2;
    const int scolL = (lane & 3) * 8;

    // stage half g (3 gload_lds per thread). Gate halves: g<4.
    auto stage_any = [&](int g, bool gate) {
        const f16* A = gate ? tu : hc;
        const f16* B = gate ? v16 : e16;
        const int stride = gate ? kD2 : kDM;
        const int colb = (gate ? g : (g - 4)) * 32 + scolL;
        const int slot = g & 3;
        #pragma unroll
        for (int i = 0; i < 2; ++i) {
            const int c = wave * 2 + i;         // A chunk 0..15 (16 rows each)
            const f16* src = A + (size_t)(aRowBase + c * 16 + srowL) * stride + colb;
            __builtin_amdgcn_global_load_lds(
                (const __attribute__((address_space(1))) void*)src,
                (__attribute__((address_space(3))) void*)(&sA[slot][c * 512]), 16, 0, 0);
        }
        const f16* srcb = B + (size_t)(vBase + wave * 16 + srowL) * stride + colb;
        __builtin_amdgcn_global_load_lds(
            (const __attribute__((address_space(1))) void*)srcb,
            (__attribute__((address_space(3))) void*)(&sB[slot][wave * 512]), 16, 0, 0);
    };
    auto stage = [&](int g) { stage_any(g, g < 4); };      // g literal at call
    auto stage_d = [&](int g) { stage_any(g, false); };    // dots-only

#define PHASE(G, ACC, DO_STAGE, STG_FN, VM)                                   \
    {                                                                         \
        const int slot_ = (G) & 3;                                            \
        const f16* __restrict__ pa_ = &sA[slot_][0];                          \
        const f16* __restrict__ pb_ = &sB[slot_][0];                          \
        f16x8 a_[4], b_[4];                                                   \
        _Pragma("unroll")                                                     \
        for (int m = 0; m < 4; ++m)                                           \
            a_[m] = *reinterpret_cast<const f16x8*>(                          \
                pa_ + (wm * 64 + m * 16 + fr) * 32 + fq * 8);                 \
        _Pragma("unroll")                                                     \
        for (int n = 0; n < 4; ++n)                                           \
            b_[n] = *reinterpret_cast<const f16x8*>(                          \
                pb_ + (wc * 64 + n * 16 + fr) * 32 + fq * 8);                 \
        if (DO_STAGE) STG_FN((G) + 3);                                        \
        asm volatile("s_waitcnt vmcnt(" VM ")" ::: "memory");                 \
        __builtin_amdgcn_s_barrier();                                         \
        asm volatile("" ::: "memory");                                        \
        __builtin_amdgcn_s_setprio(1);                                        \
        _Pragma("unroll")                                                     \
        for (int m = 0; m < 4; ++m)                                           \
            _Pragma("unroll")                                                 \
            for (int n = 0; n < 4; ++n)                                       \
                ACC[m][n] = __builtin_amdgcn_mfma_f32_16x16x32_f16(           \
                    a_[m], b_[n], ACC[m][n], 0, 0, 0);                        \
        __builtin_amdgcn_s_setprio(0);                                        \
        asm volatile("" ::: "memory");                                        \
        __builtin_amdgcn_s_barrier();                                         \
        asm volatile("" ::: "memory");                                        \
    }

    f32x4 acc[4][4];
    const f32x4 zz = {0.f, 0.f, 0.f, 0.f};
    #pragma unroll
    for (int m = 0; m < 4; ++m)
        #pragma unroll
        for (int n = 0; n < 4; ++n) acc[m][n] = zz;

    // ---------------- prologue: halves 0,1,2 in flight ----------------
    stage(0); stage(1); stage(2);
    asm volatile("s_waitcnt vmcnt(6)" ::: "memory");   // half 0 resident
    __builtin_amdgcn_s_barrier();
    asm volatile("" ::: "memory");

    // ---------------- gate phases: halves 0..3 (D2 = 128) ----------------
    PHASE(0, acc, true, stage, "6");
    PHASE(1, acc, true, stage, "6");
    PHASE(2, acc, true, stage, "6");
    PHASE(3, acc, true, stage, "6");

    // ---------------- pi conversion (registers only) ----------------
    uint pi01[4][4], pi23[4][4];
    {
        const int btB = bx * 64 + wm * 16;
        float4 bb[4];
        #pragma unroll
        for (int n = 0; n < 4; ++n) {
            const int v = vBase + wc * 64 + n * 16 + fr;
            bb[n] = *reinterpret_cast<const float4*>(bmat + (size_t)v * 4);
        }
        #pragma unroll
        for (int m = 0; m < 4; ++m) {
            const float4 ugv = *reinterpret_cast<const float4*>(ug + (btB + m * 4 + fq) * 4);
            #pragma unroll
            for (int n = 0; n < 4; ++n) {
                const float l0 = acc[m][n][0] + ugv.x + bb[n].x;
                const float l1 = acc[m][n][1] + ugv.y + bb[n].y;
                const float l2 = acc[m][n][2] + ugv.z + bb[n].z;
                const float g0 = 1.f / (1.f + __expf(-l0));
                const float g1 = 1.f / (1.f + __expf(-l1));
                const float g2 = 1.f / (1.f + __expf(-l2));
                pi01[m][n] = packf16x2(g0 * g1, g0 * (1.f - g1));
                pi23[m][n] = packf16x2((1.f - g0) * g2, (1.f - g0) * (1.f - g2));
            }
        }
    }
    #pragma unroll
    for (int m = 0; m < 4; ++m)
        #pragma unroll
        for (int n = 0; n < 4; ++n) acc[m][n] = zz;

    // ---------------- dots phases: halves 4..35 (DM = 1024) ----------------
    for (int gg = 4; gg < 32; gg += 4) {
        PHASE(gg + 0, acc, true, stage_d, "6");
        PHASE(gg + 1, acc, true, stage_d, "6");
        PHASE(gg + 2, acc, true, stage_d, "6");
        PHASE(gg + 3, acc, true, stage_d, "6");
    }
    PHASE(32, acc, true,  stage_d, "6");   // stages half 35 (last)
    PHASE(33, acc, false, stage_d, "3");
    PHASE(34, acc, false, stage_d, "0");
    PHASE(35, acc, false, stage_d, "0");
#undef PHASE

    // ---------------- epilogue: logits ----------------
    const int btB = bx * 64 + wm * 16;
    #pragma unroll
    for (int m = 0; m < 4; ++m) {
        const int bt = btB + m * 4 + fq;
        #pragma unroll
        for (int n = 0; n < 4; ++n) {
            const int v = vBase + wc * 64 + n * 16 + fr;
            union { uint u; f16 h[2]; } p01, p23;
            p01.u = pi01[m][n]; p23.u = pi23[m][n];
            const float lg = (float)p01.h[0] * acc[m][n][0]
                           + (float)p01.h[1] * acc[m][n][1]
                           + (float)p23.h[0] * acc[m][n][2]
                           + (float)p23.h[1] * acc[m][n][3];
            out[(size_t)bt * kV + v] = lg;
        }
    }
}

// ---------------------------------------------------------------------------
// softmax over V per row, in place. 2 passes (logits bounded ~|5|, exp-safe
// without max subtraction).
// ---------------------------------------------------------------------------
__global__ __launch_bounds__(256) void softmax_kernel(float* __restrict__ out)
{
    __shared__ float red[4];
    float* row = out + (size_t)blockIdx.x * kV;
    const int tid = threadIdx.x;

    float s = 0.f;
    for (int i = tid * 4; i < kV; i += 1024) {
        const float4 x = *reinterpret_cast<const float4*>(row + i);
        s += __expf(x.x) + __expf(x.y) + __expf(x.z) + __expf(x.w);
    }
    #pragma unroll
    for (int o = 1; o < 64; o <<= 1) s += __shfl_xor(s, o);
    if ((tid & 63) == 0) red[tid >> 6] = s;
    __syncthreads();
    s = red[0] + red[1] + red[2] + red[3];
    const float inv = 1.f / s;

    for (int i = tid * 4; i < kV; i += 1024) {
        const float4 x = *reinterpret_cast<const float4*>(row + i);
        float4 y;
        y.x = __expf(x.x) * inv;
        y.y = __expf(x.y) * inv;
        y.z = __expf(x.z) * inv;
        y.w = __expf(x.w) * inv;
        *reinterpret_cast<float4*>(row + i) = y;
    }
}

} // namespace

extern "C" void kernel_launch(void* const* d_in, const int* in_sizes, int n_in,
                              void* d_out, int out_size, void* d_ws, size_t ws_size,
                              hipStream_t stream)
{
    (void)in_sizes; (void)n_in; (void)out_size; (void)ws_size;
    const float* gc   = (const float*)d_in[0];
    const float* Hm   = (const float*)d_in[1];
    const float* Um   = (const float*)d_in[2];
    const float* vmat = (const float*)d_in[3];
    const float* um   = (const float*)d_in[4];
    const float* bmat = (const float*)d_in[5];
    const float* emb  = (const float*)d_in[6];
    float* out = (float*)d_out;

    size_t off = 0;
    auto take = [&](size_t bytes) -> char* {
        char* p = (char*)d_ws + off;
        off += (bytes + 255) & ~(size_t)255;
        return p;
    };
    f16*   hc  = (f16*)  take((size_t)AR * kDM * 2);   // 8 MB
    f16*   tu  = (f16*)  take((size_t)AR * kD2 * 2);   // 1 MB
    f16*   v16 = (f16*)  take((size_t)kV * kD2 * 2);   // 8 MB
    f16*   e16 = (f16*)  take((size_t)kV * kDM * 2);   // 64 MB
    float* ug  = (float*)take((size_t)AR * 4);

    prep_gemm<<<dim3(kBT / 8, 2), 256, 0, stream>>>(gc, Hm, Um, um, hc, tu, ug);
    cvt_kernel<<<(kV * kD2 / 8 + 255) / 256, 256, 0, stream>>>(vmat, v16, kV * kD2 / 8);
    cvt_kernel<<<(kV * kDM / 8 + 255) / 256, 256, 0, stream>>>(emb, e16, kV * kDM / 8);
    fused_mfma<<<dim3((AR / 256) * (kV / 128)), 512, 0, stream>>>(
        hc, tu, v16, e16, ug, bmat, out);
    softmax_kernel<<<dim3(kBT), 256, 0, stream>>>(out);
}

// Round 7
// 600.412 us; speedup vs baseline: 1.0515x; 1.0515x over previous
//
#include <hip/hip_runtime.h>
#include <math.h>

namespace {

typedef _Float16 f16;
typedef _Float16 f16x8 __attribute__((ext_vector_type(8)));
typedef float    f32x4 __attribute__((ext_vector_type(4)));

constexpr int kBT = 1024, kD1 = 256, kD2 = 128, kDM = 1024, kV = 32000, kK = 4;
constexpr int AR = kBT * kK;                    // 4096 rows of (bt,k)
constexpr int ROWS_H = kK * kDM;                // 4096
constexpr int ROWS_U = kK * kD2;                // 512
constexpr int ROWS_ALL = ROWS_H + ROWS_U + kK;  // 4612
constexpr int HALF_ROWS = ROWS_ALL / 2;         // 2306
constexpr int NBY = kV / 128;                   // 250 v-panels

// ---------------------------------------------------------------------------
// prep_gemm: hc/tU/ug from gc (fp32 accumulate, fp16 store).
// ---------------------------------------------------------------------------
__global__ __launch_bounds__(256) void prep_gemm(
    const float* __restrict__ gc, const float* __restrict__ Hm,
    const float* __restrict__ Um, const float* __restrict__ um,
    f16* __restrict__ hc, f16* __restrict__ tu, float* __restrict__ ug)
{
    __shared__ float sgc[8][kD1];
    const int btBase = blockIdx.x * 8;
    for (int idx = threadIdx.x; idx < 8 * kD1; idx += 256)
        sgc[idx / kD1][idx % kD1] = gc[(size_t)btBase * kD1 + idx];
    __syncthreads();

    const int rStart = blockIdx.y * HALF_ROWS;
    const int rEnd   = rStart + HALF_ROWS;
    for (int r = rStart + (int)threadIdx.x; r < rEnd; r += 256) {
        const float* wrow;
        if (r < ROWS_H)               wrow = Hm + (size_t)r * kD1;
        else if (r < ROWS_H + ROWS_U) wrow = Um + (size_t)(r - ROWS_H) * kD1;
        else                          wrow = um + (size_t)(r - ROWS_H - ROWS_U) * kD1;

        float acc[8] = {0.f,0.f,0.f,0.f,0.f,0.f,0.f,0.f};
        for (int i = 0; i < kD1; i += 4) {
            const float4 w = *reinterpret_cast<const float4*>(wrow + i);
            #pragma unroll
            for (int b = 0; b < 8; ++b) {
                const float4 g = *reinterpret_cast<const float4*>(&sgc[b][i]);
                acc[b] = fmaf(w.x, g.x, acc[b]);
                acc[b] = fmaf(w.y, g.y, acc[b]);
                acc[b] = fmaf(w.z, g.z, acc[b]);
                acc[b] = fmaf(w.w, g.w, acc[b]);
            }
        }
        #pragma unroll
        for (int b = 0; b < 8; ++b) {
            const int bt = btBase + b;
            if (r < ROWS_H) {
                const int k = r >> 10, d = r & 1023;
                hc[((size_t)(bt * kK + k) << 10) + d] = (f16)tanhf(acc[b]);
            } else if (r < ROWS_H + ROWS_U) {
                const int r2 = r - ROWS_H;
                const int k = r2 >> 7, j = r2 & 127;
                tu[(size_t)(bt * kK + k) * kD2 + j] = (f16)tanhf(acc[b]);
            } else {
                ug[bt * kK + (r - ROWS_H - ROWS_U)] = acc[b];
            }
        }
    }
}

// ---------------------------------------------------------------------------
// cvt_kernel: fp32 -> fp16, 8 elems/thread.
// ---------------------------------------------------------------------------
__global__ __launch_bounds__(256) void cvt_kernel(
    const float* __restrict__ src, f16* __restrict__ dst, int n8)
{
    const int i = blockIdx.x * 256 + threadIdx.x;
    if (i >= n8) return;
    const float4 x0 = *reinterpret_cast<const float4*>(src + (size_t)i * 8);
    const float4 x1 = *reinterpret_cast<const float4*>(src + (size_t)i * 8 + 4);
    union { f16 h[8]; uint4 v; } u;
    u.h[0] = (f16)x0.x; u.h[1] = (f16)x0.y; u.h[2] = (f16)x0.z; u.h[3] = (f16)x0.w;
    u.h[4] = (f16)x1.x; u.h[5] = (f16)x1.y; u.h[6] = (f16)x1.z; u.h[7] = (f16)x1.w;
    *reinterpret_cast<uint4*>(dst + (size_t)i * 8) = u.v;
}

__device__ __forceinline__ uint packf16x2(float a, float b) {
    union { f16 h[2]; uint u; } z;
    z.h[0] = (f16)a; z.h[1] = (f16)b;
    return z.u;
}

// ---------------------------------------------------------------------------
// fused_mfma: gate GEMM (K=128) + dots GEMM (K=1024), one 36-half stream.
// BM=256 A-rows x BN=128 v, 32-col halves; 8 waves (4M x 2N), wave-tile 64x64.
// LDS: ring of 4 half-slots, A 16KB + B 8KB each = 96 KiB.
//
// SWIZZLE (fixes round-6's 8-way read conflict): rows are 32 f16 = 64 B =
// 4 x 16B slots. Logical col-block q of row r lives at phys slot q ^ s(r),
// s(r) = (r>>1)&3. Read: lane (fr,fq) reads row ..+fr, phys slot
// fq ^ ((fr>>1)&3); unit mod 8 = 4(fr&1) + fq^s -> for fixed fq the 16 fr
// lanes cover each 16B unit class exactly twice = conflict-free (2-way free).
// Write: gload_lds is linear (lane l -> row l>>2, slot l&3); the per-lane
// GLOBAL source col is inverse-swizzled: ((l&3) ^ ((l>>3)&3)) * 8.
//
// Pipeline: 3 halves ahead, 3 loads/half/thread, per phase:
//   {8x ds_read_b128; issue stage of half g+3; s_waitcnt vmcnt(6); s_barrier;
//    setprio(1); 16 MFMA; setprio(0); s_barrier}
// vmcnt(6) at phase g retires half g+1. Tail: 6 -> 3 -> 0.
// bmat/ug are prefetched after PHASE(1) (2 phases before use) so the pi
// block's wait-on-use never drains the staging queue.
// A rows = (bt*4+k): acc reg j = mixture component k of one (bt,v).
// Epilogue: raw logits -> out; per-(bt,block) sum of exp -> psum
// [bt*512 + by*2 + wc] so softmax skips its sum pass.
// ---------------------------------------------------------------------------
__global__ __launch_bounds__(512, 2) void fused_mfma(
    const f16* __restrict__ hc,  const f16* __restrict__ tu,
    const f16* __restrict__ v16, const f16* __restrict__ e16,
    const float* __restrict__ ug, const float* __restrict__ bmat,
    float* __restrict__ out, float* __restrict__ psum)
{
    __shared__ __align__(16) f16 sA[4][256 * 32];   // 64 KiB
    __shared__ __align__(16) f16 sB[4][128 * 32];   // 32 KiB

    const int tid  = threadIdx.x;
    const int lane = tid & 63;
    const int wave = tid >> 6;
    const int fr = lane & 15, fq = lane >> 4;
    const int wm = wave >> 1, wc = wave & 1;

    // plain 2D grid: bx fastest -> 16 consecutive blocks share one B-panel
    // (round-5's proven locality; FETCH was 335 MB there vs 619 in round 6).
    const int bx = blockIdx.x;            // 0..15
    const int by = blockIdx.y;            // 0..249
    const int aRowBase = bx * 256;
    const int vBase    = by * 128;
    const int btB      = bx * 64 + wm * 16;

    // staging lane geometry: linear LDS dest, inverse-swizzled global col.
    const int srowL = lane >> 2;                          // row in 16-row chunk
    const int scolL = ((lane & 3) ^ ((lane >> 3) & 3)) * 8;

    // read-side swizzle term (lane-constant).
    const int rslot = (fq ^ ((fr >> 1) & 3)) * 8;

    auto stage_any = [&](int g, bool gate) {
        const f16* A = gate ? tu : hc;
        const f16* B = gate ? v16 : e16;
        const int stride = gate ? kD2 : kDM;
        const int colb = (gate ? g : (g - 4)) * 32 + scolL;
        const int slot = g & 3;
        #pragma unroll
        for (int i = 0; i < 2; ++i) {
            const int c = wave * 2 + i;         // A chunk 0..15 (16 rows each)
            const f16* src = A + (size_t)(aRowBase + c * 16 + srowL) * stride + colb;
            __builtin_amdgcn_global_load_lds(
                (const __attribute__((address_space(1))) void*)src,
                (__attribute__((address_space(3))) void*)(&sA[slot][c * 512]), 16, 0, 0);
        }
        const f16* srcb = B + (size_t)(vBase + wave * 16 + srowL) * stride + colb;
        __builtin_amdgcn_global_load_lds(
            (const __attribute__((address_space(1))) void*)srcb,
            (__attribute__((address_space(3))) void*)(&sB[slot][wave * 512]), 16, 0, 0);
    };
    auto stage = [&](int g) { stage_any(g, g < 4); };
    auto stage_d = [&](int g) { stage_any(g, false); };

#define PHASE(G, ACC, DO_STAGE, STG_FN, VM)                                   \
    {                                                                         \
        const int slot_ = (G) & 3;                                            \
        const f16* __restrict__ pa_ = &sA[slot_][0];                          \
        const f16* __restrict__ pb_ = &sB[slot_][0];                          \
        f16x8 a_[4], b_[4];                                                   \
        _Pragma("unroll")                                                     \
        for (int m = 0; m < 4; ++m)                                           \
            a_[m] = *reinterpret_cast<const f16x8*>(                          \
                pa_ + (wm * 64 + m * 16 + fr) * 32 + rslot);                  \
        _Pragma("unroll")                                                     \
        for (int n = 0; n < 4; ++n)                                           \
            b_[n] = *reinterpret_cast<const f16x8*>(                          \
                pb_ + (wc * 64 + n * 16 + fr) * 32 + rslot);                  \
        if (DO_STAGE) STG_FN((G) + 3);                                        \
        asm volatile("s_waitcnt vmcnt(" VM ")" ::: "memory");                 \
        __builtin_amdgcn_s_barrier();                                         \
        asm volatile("" ::: "memory");                                        \
        __builtin_amdgcn_s_setprio(1);                                        \
        _Pragma("unroll")                                                     \
        for (int m = 0; m < 4; ++m)                                           \
            _Pragma("unroll")                                                 \
            for (int n = 0; n < 4; ++n)                                       \
                ACC[m][n] = __builtin_amdgcn_mfma_f32_16x16x32_f16(           \
                    a_[m], b_[n], ACC[m][n], 0, 0, 0);                        \
        __builtin_amdgcn_s_setprio(0);                                        \
        asm volatile("" ::: "memory");                                        \
        __builtin_amdgcn_s_barrier();                                         \
        asm volatile("" ::: "memory");                                        \
    }

    f32x4 acc[4][4];
    const f32x4 zz = {0.f, 0.f, 0.f, 0.f};
    #pragma unroll
    for (int m = 0; m < 4; ++m)
        #pragma unroll
        for (int n = 0; n < 4; ++n) acc[m][n] = zz;

    // ---------------- prologue: halves 0,1,2 in flight ----------------
    stage(0); stage(1); stage(2);
    asm volatile("s_waitcnt vmcnt(6)" ::: "memory");   // half 0 resident
    __builtin_amdgcn_s_barrier();
    asm volatile("" ::: "memory");

    // ---------------- gate phases: halves 0..3 (D2 = 128) ----------------
    PHASE(0, acc, true, stage, "6");
    PHASE(1, acc, true, stage, "6");

    // prefetch epilogue operands 2 phases before use (keeps the pi block's
    // wait-on-use from draining the staging queue).
    float4 bb[4], ugv[4];
    #pragma unroll
    for (int n = 0; n < 4; ++n)
        bb[n] = *reinterpret_cast<const float4*>(
            bmat + (size_t)(vBase + wc * 64 + n * 16 + fr) * 4);
    #pragma unroll
    for (int m = 0; m < 4; ++m)
        ugv[m] = *reinterpret_cast<const float4*>(ug + (btB + m * 4 + fq) * 4);

    PHASE(2, acc, true, stage, "6");
    PHASE(3, acc, true, stage, "6");

    // ---------------- pi conversion (registers only) ----------------
    uint pi01[4][4], pi23[4][4];
    #pragma unroll
    for (int m = 0; m < 4; ++m) {
        #pragma unroll
        for (int n = 0; n < 4; ++n) {
            const float l0 = acc[m][n][0] + ugv[m].x + bb[n].x;
            const float l1 = acc[m][n][1] + ugv[m].y + bb[n].y;
            const float l2 = acc[m][n][2] + ugv[m].z + bb[n].z;
            const float g0 = 1.f / (1.f + __expf(-l0));
            const float g1 = 1.f / (1.f + __expf(-l1));
            const float g2 = 1.f / (1.f + __expf(-l2));
            pi01[m][n] = packf16x2(g0 * g1, g0 * (1.f - g1));
            pi23[m][n] = packf16x2((1.f - g0) * g2, (1.f - g0) * (1.f - g2));
        }
    }
    #pragma unroll
    for (int m = 0; m < 4; ++m)
        #pragma unroll
        for (int n = 0; n < 4; ++n) acc[m][n] = zz;

    // ---------------- dots phases: halves 4..35 (DM = 1024) ----------------
    for (int gg = 4; gg < 32; gg += 4) {
        PHASE(gg + 0, acc, true, stage_d, "6");
        PHASE(gg + 1, acc, true, stage_d, "6");
        PHASE(gg + 2, acc, true, stage_d, "6");
        PHASE(gg + 3, acc, true, stage_d, "6");
    }
    PHASE(32, acc, true,  stage_d, "6");   // stages half 35 (last)
    PHASE(33, acc, false, stage_d, "3");
    PHASE(34, acc, false, stage_d, "0");
    PHASE(35, acc, false, stage_d, "0");
#undef PHASE

    // ---------------- epilogue: logits + exp partial sums ----------------
    #pragma unroll
    for (int m = 0; m < 4; ++m) {
        const int bt = btB + m * 4 + fq;
        float es = 0.f;
        #pragma unroll
        for (int n = 0; n < 4; ++n) {
            const int v = vBase + wc * 64 + n * 16 + fr;
            union { uint u; f16 h[2]; } p01, p23;
            p01.u = pi01[m][n]; p23.u = pi23[m][n];
            const float lg = (float)p01.h[0] * acc[m][n][0]
                           + (float)p01.h[1] * acc[m][n][1]
                           + (float)p23.h[0] * acc[m][n][2]
                           + (float)p23.h[1] * acc[m][n][3];
            out[(size_t)bt * kV + v] = lg;
            es += __expf(lg);
        }
        // reduce over the 16-lane fr group (same bt); masks <16 stay in group.
        es += __shfl_xor(es, 1);
        es += __shfl_xor(es, 2);
        es += __shfl_xor(es, 4);
        es += __shfl_xor(es, 8);
        if (fr == 0)
            psum[(size_t)bt * 512 + by * 2 + wc] = es;
    }
}

// ---------------------------------------------------------------------------
// softmax scale pass: denominator from psum partials (1 sum pass saved).
// ---------------------------------------------------------------------------
__global__ __launch_bounds__(256) void softmax_kernel(
    float* __restrict__ out, const float* __restrict__ psum)
{
    __shared__ float red[4];
    const int bt = blockIdx.x;
    float* row = out + (size_t)bt * kV;
    const int tid = threadIdx.x;

    float s = 0.f;
    for (int i = tid; i < 2 * NBY; i += 256) s += psum[(size_t)bt * 512 + i];
    #pragma unroll
    for (int o = 1; o < 64; o <<= 1) s += __shfl_xor(s, o);
    if ((tid & 63) == 0) red[tid >> 6] = s;
    __syncthreads();
    s = red[0] + red[1] + red[2] + red[3];
    const float inv = 1.f / s;

    for (int i = tid * 4; i < kV; i += 1024) {
        const float4 x = *reinterpret_cast<const float4*>(row + i);
        float4 y;
        y.x = __expf(x.x) * inv;
        y.y = __expf(x.y) * inv;
        y.z = __expf(x.z) * inv;
        y.w = __expf(x.w) * inv;
        *reinterpret_cast<float4*>(row + i) = y;
    }
}

} // namespace

extern "C" void kernel_launch(void* const* d_in, const int* in_sizes, int n_in,
                              void* d_out, int out_size, void* d_ws, size_t ws_size,
                              hipStream_t stream)
{
    (void)in_sizes; (void)n_in; (void)out_size; (void)ws_size;
    const float* gc   = (const float*)d_in[0];
    const float* Hm   = (const float*)d_in[1];
    const float* Um   = (const float*)d_in[2];
    const float* vmat = (const float*)d_in[3];
    const float* um   = (const float*)d_in[4];
    const float* bmat = (const float*)d_in[5];
    const float* emb  = (const float*)d_in[6];
    float* out = (float*)d_out;

    size_t off = 0;
    auto take = [&](size_t bytes) -> char* {
        char* p = (char*)d_ws + off;
        off += (bytes + 255) & ~(size_t)255;
        return p;
    };
    f16*   hc   = (f16*)  take((size_t)AR * kDM * 2);   // 8 MB
    f16*   tu   = (f16*)  take((size_t)AR * kD2 * 2);   // 1 MB
    f16*   v16  = (f16*)  take((size_t)kV * kD2 * 2);   // 8 MB
    f16*   e16  = (f16*)  take((size_t)kV * kDM * 2);   // 64 MB
    float* ug   = (float*)take((size_t)AR * 4);
    float* psum = (float*)take((size_t)kBT * 512 * 4);  // 2 MB

    prep_gemm<<<dim3(kBT / 8, 2), 256, 0, stream>>>(gc, Hm, Um, um, hc, tu, ug);
    cvt_kernel<<<(kV * kD2 / 8 + 255) / 256, 256, 0, stream>>>(vmat, v16, kV * kD2 / 8);
    cvt_kernel<<<(kV * kDM / 8 + 255) / 256, 256, 0, stream>>>(emb, e16, kV * kDM / 8);
    fused_mfma<<<dim3(AR / 256, NBY), 512, 0, stream>>>(
        hc, tu, v16, e16, ug, bmat, out, psum);
    softmax_kernel<<<dim3(kBT), 256, 0, stream>>>(out, psum);
}